// Round 2
// baseline (82.846 us; speedup 1.0000x reference)
//
#include <hip/hip_runtime.h>
#include <cmath>

#define B_ 32
#define S_ 4096
#define E_ 512
#define H_ 1024
#define NCHUNK 64   // blocks per batch row for attn partials

// ---------------------------------------------------------------------------
// Kernel 1: v_t[b,e] = tanhf(dot(h[b,:], W[e,:]) + bias[e])
// One wave per output element; lane reads 16 contiguous f32 (4x float4).
// ---------------------------------------------------------------------------
__global__ __launch_bounds__(256) void vt_kernel(const float* __restrict__ h,
                                                 const float* __restrict__ W,
                                                 const float* __restrict__ bias,
                                                 float* __restrict__ vt) {
    int wid  = threadIdx.x >> 6;
    int lane = threadIdx.x & 63;
    int out  = blockIdx.x * 4 + wid;        // 0 .. B*E-1
    int b    = out >> 9;                    // / E_
    int e    = out & (E_ - 1);
    const float* hrow = h + b * H_;
    const float* wrow = W + (size_t)e * H_;
    int base = lane * 16;
    float acc = 0.f;
#pragma unroll
    for (int j = 0; j < 4; ++j) {
        float4 hv = *reinterpret_cast<const float4*>(hrow + base + j * 4);
        float4 wv = *reinterpret_cast<const float4*>(wrow + base + j * 4);
        acc += hv.x * wv.x + hv.y * wv.y + hv.z * wv.z + hv.w * wv.w;
    }
#pragma unroll
    for (int off = 32; off > 0; off >>= 1) acc += __shfl_xor(acc, off, 64);
    if (lane == 0) vt[out] = tanhf(acc + bias[e]);
}

// ---------------------------------------------------------------------------
// Kernel 2: fused gather + scores + online softmax + weighted accumulate.
// Block = 4 waves; each wave owns 16 consecutive rows, processed 4 at a time
// (R=4): 8 row-loads in flight, 4 interleaved shuffle-reduce chains, one
// combined online-softmax update. Block-combine via LDS -> partial {m,l,acc}.
// ---------------------------------------------------------------------------
__global__ __launch_bounds__(256) void attn_part_kernel(const int* __restrict__ mems,
                                                        const float* __restrict__ emb,
                                                        const float* __restrict__ vt,
                                                        float* __restrict__ partial,
                                                        int nchunk) {
    int b     = blockIdx.x / nchunk;
    int chunk = blockIdx.x % nchunk;
    int wid   = threadIdx.x >> 6;
    int lane  = threadIdx.x & 63;
    int rows_per_block = S_ / nchunk;            // 64 at nchunk=64
    int rows_per_wave  = rows_per_block / 4;     // 16
    int s0 = chunk * rows_per_block + wid * rows_per_wave;

    const float* vrow = vt + (size_t)b * E_ + lane * 8;
    float4 v0 = *reinterpret_cast<const float4*>(vrow);
    float4 v1 = *reinterpret_cast<const float4*>(vrow + 4);

    float m = -1e30f, l = 0.f;
    float4 acc0 = {0.f, 0.f, 0.f, 0.f};
    float4 acc1 = {0.f, 0.f, 0.f, 0.f};

    const int* midx = mems + (size_t)b * S_;

    for (int it = 0; it < rows_per_wave; it += 4) {
        int s = s0 + it;
        int4 idx4 = *reinterpret_cast<const int4*>(midx + s);
        const float* r0p = emb + (size_t)idx4.x * E_ + lane * 8;
        const float* r1p = emb + (size_t)idx4.y * E_ + lane * 8;
        const float* r2p = emb + (size_t)idx4.z * E_ + lane * 8;
        const float* r3p = emb + (size_t)idx4.w * E_ + lane * 8;
        float4 a0 = *reinterpret_cast<const float4*>(r0p);
        float4 b0 = *reinterpret_cast<const float4*>(r0p + 4);
        float4 a1 = *reinterpret_cast<const float4*>(r1p);
        float4 b1 = *reinterpret_cast<const float4*>(r1p + 4);
        float4 a2 = *reinterpret_cast<const float4*>(r2p);
        float4 b2 = *reinterpret_cast<const float4*>(r2p + 4);
        float4 a3 = *reinterpret_cast<const float4*>(r3p);
        float4 b3 = *reinterpret_cast<const float4*>(r3p + 4);

        float p0 = a0.x*v0.x + a0.y*v0.y + a0.z*v0.z + a0.w*v0.w
                 + b0.x*v1.x + b0.y*v1.y + b0.z*v1.z + b0.w*v1.w;
        float p1 = a1.x*v0.x + a1.y*v0.y + a1.z*v0.z + a1.w*v0.w
                 + b1.x*v1.x + b1.y*v1.y + b1.z*v1.z + b1.w*v1.w;
        float p2 = a2.x*v0.x + a2.y*v0.y + a2.z*v0.z + a2.w*v0.w
                 + b2.x*v1.x + b2.y*v1.y + b2.z*v1.z + b2.w*v1.w;
        float p3 = a3.x*v0.x + a3.y*v0.y + a3.z*v0.z + a3.w*v0.w
                 + b3.x*v1.x + b3.y*v1.y + b3.z*v1.z + b3.w*v1.w;

#pragma unroll
        for (int off = 32; off > 0; off >>= 1) {
            p0 += __shfl_xor(p0, off, 64);
            p1 += __shfl_xor(p1, off, 64);
            p2 += __shfl_xor(p2, off, 64);
            p3 += __shfl_xor(p3, off, 64);
        }

        float pm    = fmaxf(fmaxf(p0, p1), fmaxf(p2, p3));
        float m_new = fmaxf(m, pm);
        float corr  = __expf(m - m_new);
        float w0 = __expf(p0 - m_new);
        float w1 = __expf(p1 - m_new);
        float w2 = __expf(p2 - m_new);
        float w3 = __expf(p3 - m_new);
        l = l * corr + (w0 + w1) + (w2 + w3);
        acc0.x = acc0.x * corr + w0*a0.x + w1*a1.x + w2*a2.x + w3*a3.x;
        acc0.y = acc0.y * corr + w0*a0.y + w1*a1.y + w2*a2.y + w3*a3.y;
        acc0.z = acc0.z * corr + w0*a0.z + w1*a1.z + w2*a2.z + w3*a3.z;
        acc0.w = acc0.w * corr + w0*a0.w + w1*a1.w + w2*a2.w + w3*a3.w;
        acc1.x = acc1.x * corr + w0*b0.x + w1*b1.x + w2*b2.x + w3*b3.x;
        acc1.y = acc1.y * corr + w0*b0.y + w1*b1.y + w2*b2.y + w3*b3.y;
        acc1.z = acc1.z * corr + w0*b0.z + w1*b1.z + w2*b2.z + w3*b3.z;
        acc1.w = acc1.w * corr + w0*b0.w + w1*b1.w + w2*b2.w + w3*b3.w;
        m = m_new;
    }

    // --- block combine across the 4 waves ---
    __shared__ float s_m[4], s_l[4];
    __shared__ float s_acc[4][E_];
    if (lane == 0) { s_m[wid] = m; s_l[wid] = l; }
    float* dst = &s_acc[wid][lane * 8];
    reinterpret_cast<float4*>(dst)[0] = acc0;
    reinterpret_cast<float4*>(dst)[1] = acc1;
    __syncthreads();

    float mb = fmaxf(fmaxf(s_m[0], s_m[1]), fmaxf(s_m[2], s_m[3]));
    float f0 = __expf(s_m[0] - mb);
    float f1 = __expf(s_m[1] - mb);
    float f2 = __expf(s_m[2] - mb);
    float f3 = __expf(s_m[3] - mb);
    float lb = s_l[0] * f0 + s_l[1] * f1 + s_l[2] * f2 + s_l[3] * f3;

    float* base = partial + (size_t)(b * nchunk + chunk) * (E_ + 2);
    if (threadIdx.x == 0) { base[0] = mb; base[1] = lb; }
    for (int e = threadIdx.x; e < E_; e += 256) {
        base[2 + e] = s_acc[0][e] * f0 + s_acc[1][e] * f1
                    + s_acc[2][e] * f2 + s_acc[3][e] * f3;
    }
}

// ---------------------------------------------------------------------------
// Kernel 3: deterministic combine. One block per b, thread per e (512 thr);
// scalar m/l loads broadcast, acc loads coalesced across threads.
// ---------------------------------------------------------------------------
__global__ __launch_bounds__(512) void combine_kernel(const float* __restrict__ partial,
                                                      float* __restrict__ out,
                                                      int nchunk) {
    int b = blockIdx.x;
    int e = threadIdx.x;
    const int P = E_ + 2;
    const float* base = partial + (size_t)b * nchunk * P;
    float m_g = -1e30f;
    for (int c = 0; c < nchunk; ++c)
        m_g = fmaxf(m_g, base[(size_t)c * P]);
    float L = 0.f, s = 0.f;
    for (int c = 0; c < nchunk; ++c) {
        const float* p = base + (size_t)c * P;
        float f = __expf(p[0] - m_g);
        L += p[1] * f;
        s += f * p[2 + e];
    }
    out[(size_t)b * E_ + e] = s / L;
}

extern "C" void kernel_launch(void* const* d_in, const int* in_sizes, int n_in,
                              void* d_out, int out_size, void* d_ws, size_t ws_size,
                              hipStream_t stream) {
    const float* h    = (const float*)d_in[0];   // [B,H]
    const int*   mems = (const int*)d_in[1];     // [B,S]
    const float* emb  = (const float*)d_in[2];   // [V,E]
    const float* W    = (const float*)d_in[3];   // [E,H]
    const float* bias = (const float*)d_in[4];   // [E]
    float* out = (float*)d_out;                  // [B,1,E]

    float* ws = (float*)d_ws;
    float* vt = ws;                              // B*E floats
    int nchunk = NCHUNK;
    while (nchunk > 1 &&
           (size_t)(B_ * E_ + B_ * nchunk * (E_ + 2)) * sizeof(float) > ws_size) {
        nchunk >>= 1;
    }
    float* partial = ws + B_ * E_;

    hipLaunchKernelGGL(vt_kernel, dim3(B_ * E_ / 4), dim3(256), 0, stream,
                       h, W, bias, vt);
    hipLaunchKernelGGL(attn_part_kernel, dim3(B_ * nchunk), dim3(256), 0, stream,
                       mems, emb, vt, partial, nchunk);
    hipLaunchKernelGGL(combine_kernel, dim3(B_), dim3(512), 0, stream,
                       partial, out, nchunk);
}